// Round 11
// baseline (1310.744 us; speedup 1.0000x reference)
//
#include <hip/hip_runtime.h>
#include <math.h>

#define HH 4
#define DD 512
#define FF 1024          // 2*DD floats per complex vector
#define NN 2048
#define KK 4
#define TMAXI 4
#define THRESHV 0.99f
#define EPSV 1e-6f

typedef unsigned short ushort_t;
typedef __attribute__((ext_vector_type(8))) __bf16 bf16x8;
typedef __attribute__((ext_vector_type(8))) _Float16 half8;
typedef __attribute__((ext_vector_type(4))) float f32x4;
typedef __attribute__((ext_vector_type(4))) unsigned short us4;

__device__ __forceinline__ unsigned short f2bf(float x) {
    unsigned int u = __float_as_uint(x);
    unsigned int r = (u + 0x7FFF + ((u >> 16) & 1)) >> 16;   // round-to-nearest-even
    return (unsigned short)r;
}

__device__ __forceinline__ float fast_rcp(float x) { return __builtin_amdgcn_rcpf(x); }

typedef __attribute__((address_space(3))) unsigned int lds_u32;
typedef __attribute__((address_space(1))) const unsigned int glb_u32;
__device__ __forceinline__ void gl_lds16(const void* g, void* s) {
    __builtin_amdgcn_global_load_lds((glb_u32*)g, (lds_u32*)s, 16, 0, 0);
}

// ---------------- u_halt norms ----------------
__global__ void k_unorm(const float* __restrict__ u_halt, float* __restrict__ norm_inv) {
    __shared__ float red[256];
    int tid = threadIdx.x;
    for (int h = 0; h < HH; ++h) {
        float s = 0.f;
        for (int i = tid; i < FF; i += 256) { float v = u_halt[h * FF + i]; s += v * v; }
        red[tid] = s; __syncthreads();
        for (int off = 128; off > 0; off >>= 1) {
            if (tid < off) red[tid] += red[tid + off];
            __syncthreads();
        }
        if (tid == 0) norm_inv[h] = 1.0f / sqrtf(red[0] + EPSV);
        __syncthreads();
    }
}

// ---------------- fp32 -> bf16 cast (vectorized x4, G13) ----------------
__global__ void k_cvt_bf4(const float* __restrict__ in, ushort_t* __restrict__ out, int total4) {
    int i = blockIdx.x * 256 + threadIdx.x;
    if (i >= total4) return;
    float4 v = ((const float4*)in)[i];
    us4 o;
    o.x = f2bf(v.x); o.y = f2bf(v.y); o.z = f2bf(v.z); o.w = f2bf(v.w);
    ((us4*)out)[i] = o;
}

// ---------------- scores GEMM (bf16 MFMA, BK=64, T2 both-sides XOR swizzle) ----------------
// C stored as f16 (round-8 win: halves the scores round-trip).
#define BM 128
#define BN 128
#define BKE 64
__global__ __launch_bounds__(256) void k_gemm_mfma(const ushort_t* __restrict__ A,
                                                   const ushort_t* __restrict__ B,
                                                   ushort_t* __restrict__ C) {
    __shared__ __align__(16) ushort_t As[BM * BKE];   // 16 KB
    __shared__ __align__(16) ushort_t Bs[BN * BKE];   // 16 KB
    int tid = threadIdx.x;
    int lane = tid & 63, w = tid >> 6;
    int row0 = blockIdx.y * BM, col0 = blockIdx.x * BN;

    int srow = lane >> 3;
    int schunk = (lane & 7) ^ srow;            // pre-swizzled global chunk
    const ushort_t* gA = A + (size_t)(row0 + w * 32 + srow) * FF + schunk * 8;
    const ushort_t* gB = B + (size_t)(col0 + w * 32 + srow) * FF + schunk * 8;
    ushort_t* sA = As + (w * 32) * BKE;
    ushort_t* sB = Bs + (w * 32) * BKE;

    int fr = lane & 15;
    int q  = lane >> 4;                        // 0..3
    int wr0 = (w >> 1) * 64, wc0 = (w & 1) * 64;

    f32x4 acc[4][4] = {};

    for (int kb = 0; kb < FF; kb += BKE) {
        #pragma unroll
        for (int i = 0; i < 4; i++) {
            gl_lds16(gA + kb + (size_t)(8 * i) * FF, sA + (8 * i) * BKE);
            gl_lds16(gB + kb + (size_t)(8 * i) * FF, sB + (8 * i) * BKE);
        }
        __syncthreads();
        bf16x8 af[2][4], bfv[2][4];
        #pragma unroll
        for (int hf = 0; hf < 2; hf++) {
            int ck = ((4 * hf + q) ^ (fr & 7)) * 8;   // swizzled short offset in row
            #pragma unroll
            for (int i = 0; i < 4; i++) {
                af[hf][i]  = *(const bf16x8*)&As[(wr0 + 16 * i + fr) * BKE + ck];
                bfv[hf][i] = *(const bf16x8*)&Bs[(wc0 + 16 * i + fr) * BKE + ck];
            }
        }
        #pragma unroll
        for (int hf = 0; hf < 2; hf++)
            #pragma unroll
            for (int i = 0; i < 4; i++)
                #pragma unroll
                for (int j = 0; j < 4; j++)
                    acc[i][j] = __builtin_amdgcn_mfma_f32_16x16x32_bf16(af[hf][i], bfv[hf][j], acc[i][j], 0, 0, 0);
        __syncthreads();
    }

    int crow = (lane >> 4) * 4;
    int ccol = lane & 15;
    #pragma unroll
    for (int i = 0; i < 4; i++)
        #pragma unroll
        for (int r = 0; r < 4; r++) {
            ushort_t* Cr = C + (size_t)(row0 + wr0 + 16 * i + crow + r) * (HH * NN) + col0 + wc0 + ccol;
            #pragma unroll
            for (int j = 0; j < 4; j++) {
                _Float16 hv = (_Float16)acc[i][j][r];
                Cr[16 * j] = *(ushort_t*)&hv;
            }
        }
}

// ---------------- softmax + top-4 per (row, head) ----------------
// One WAVE per (row, head): 2048 f16 scores -> 32 floats/lane. (round-8 proven;
// round-10 fusion into k_fused regressed −25us: softmax ran at k_fused's low
// occupancy. Keep standalone.)
__global__ __launch_bounds__(256) void k_softtop(const ushort_t* __restrict__ Sc,
                                                 float* __restrict__ topw, int* __restrict__ topi,
                                                 int row0) {
    int tid = threadIdx.x;
    int w = tid >> 6, lane = tid & 63;
    int g = blockIdx.x * 4 + w;          // (row, head) pair within chunk
    int r = g >> 2;
    int h = g & 3;
    const ushort_t* S = Sc + (size_t)r * (HH * NN) + h * NN + lane * 8;
    float f0[8], f1[8], f2[8], f3[8];
    {
        half8 h0 = *(const half8*)(S);
        half8 h1 = *(const half8*)(S + 512);
        half8 h2 = *(const half8*)(S + 1024);
        half8 h3 = *(const half8*)(S + 1536);
        #pragma unroll
        for (int e = 0; e < 8; e++) {
            f0[e] = (float)h0[e]; f1[e] = (float)h1[e];
            f2[e] = (float)h2[e]; f3[e] = (float)h3[e];
        }
    }

    // row max
    float bm = f0[0];
    #pragma unroll
    for (int e = 0; e < 8; e++) {
        bm = fmaxf(bm, fmaxf(fmaxf(f0[e], f1[e]), fmaxf(f2[e], f3[e])));
    }
    #pragma unroll
    for (int m = 1; m < 64; m <<= 1) bm = fmaxf(bm, __shfl_xor(bm, m, 64));

    // sum of exp
    float se = 0.f;
    #pragma unroll
    for (int e = 0; e < 8; e++)
        se += __expf(f0[e] - bm) + __expf(f1[e] - bm) + __expf(f2[e] - bm) + __expf(f3[e] - bm);
    #pragma unroll
    for (int m = 1; m < 64; m <<= 1) se += __shfl_xor(se, m, 64);
    float Zinv = fast_rcp(se);

    int gbh = (row0 + r) * HH + h;
    int base = lane * 8;
    #pragma unroll
    for (int k = 0; k < KK; k++) {
        float bv = -INFINITY; int bi = NN;
        #pragma unroll
        for (int e = 0; e < 8; e++) {
            if (f0[e] > bv) { bv = f0[e]; bi = base + e; }
        }
        #pragma unroll
        for (int e = 0; e < 8; e++) {
            if (f1[e] > bv) { bv = f1[e]; bi = 512 + base + e; }
        }
        #pragma unroll
        for (int e = 0; e < 8; e++) {
            if (f2[e] > bv) { bv = f2[e]; bi = 1024 + base + e; }
        }
        #pragma unroll
        for (int e = 0; e < 8; e++) {
            if (f3[e] > bv) { bv = f3[e]; bi = 1536 + base + e; }
        }
        #pragma unroll
        for (int m = 1; m < 64; m <<= 1) {
            float ov = __shfl_xor(bv, m, 64);
            int   oi = __shfl_xor(bi, m, 64);
            if (ov > bv || (ov == bv && oi < bi)) { bv = ov; bi = oi; }
        }
        if (lane == 0) {
            topw[gbh * KK + k] = __expf(bv - bm) * Zinv;
            topi[gbh * KK + k] = bi;
        }
        if (k < KK - 1) {
            #pragma unroll
            for (int e = 0; e < 8; e++) {
                if (base + e == bi)        f0[e] = -INFINITY;
                if (512 + base + e == bi)  f1[e] = -INFINITY;
                if (1024 + base + e == bi) f2[e] = -INFINITY;
                if (1536 + base + e == bi) f3[e] = -INFINITY;
            }
        }
    }
}

// ---------------- fused solve + halt + pool ----------------
// block = token b; wave w = head h; lane owns 8 complex elems.
// Solve/halt body = round-0 PROVEN version (5 structural attacks all lost to it).
// NEW round 11: (a) psi_h kept in F16 — pure internal round-trip, halves 134MB/iter
// of k_fused's traffic; elements ~0.04 scale, f16 abs err ~2e-5, two orders under
// the bf16-feat noise that dominates absmax. (b) last iter computes `out` directly
// (k_out fused away), skipping the merged store.
__global__ __launch_bounds__(256) void k_fused(const float* __restrict__ psi,
                                               ushort_t* __restrict__ psi_h,
                                               const float* __restrict__ bank_vals,
                                               const float* __restrict__ topw,
                                               const int* __restrict__ topi,
                                               const float* __restrict__ u_halt,
                                               const float* __restrict__ norm_inv,
                                               const float* __restrict__ W_halt,
                                               const float* __restrict__ b_halt,
                                               const float* __restrict__ head_mix,
                                               float* __restrict__ merged,
                                               ushort_t* __restrict__ feat,
                                               float* __restrict__ cum,
                                               float* __restrict__ cost,
                                               int* __restrict__ halted,
                                               const float* __restrict__ out_scale,
                                               float* __restrict__ outbuf,
                                               int first, int is_last) {
    __shared__ float Pn[HH][FF];     // psi_next staging (16 KB)
    __shared__ float xw[4][9];
    int b = blockIdx.x;
    int tid = threadIdx.x;
    int w = tid >> 6, lane = tid & 63;
    int bh = b * HH + w;

    float wk[KK]; int ix[KK];
    #pragma unroll
    for (int k = 0; k < KK; k++) { wk[k] = topw[bh * KK + k]; ix[k] = topi[bh * KK + k]; }

    float4 p4[4], v4[KK][4];
    if (first) {
        const float* Pr = psi + (size_t)b * FF + lane * 16;
        #pragma unroll
        for (int c = 0; c < 4; c++) p4[c] = *(const float4*)(Pr + 4 * c);
    } else {
        const ushort_t* Ph = psi_h + (size_t)bh * FF + lane * 16;
        half8 ha = *(const half8*)(Ph);
        half8 hb = *(const half8*)(Ph + 8);
        p4[0].x = (float)ha[0]; p4[0].y = (float)ha[1]; p4[0].z = (float)ha[2]; p4[0].w = (float)ha[3];
        p4[1].x = (float)ha[4]; p4[1].y = (float)ha[5]; p4[1].z = (float)ha[6]; p4[1].w = (float)ha[7];
        p4[2].x = (float)hb[0]; p4[2].y = (float)hb[1]; p4[2].z = (float)hb[2]; p4[2].w = (float)hb[3];
        p4[3].x = (float)hb[4]; p4[3].y = (float)hb[5]; p4[3].z = (float)hb[6]; p4[3].w = (float)hb[7];
    }
    #pragma unroll
    for (int k = 0; k < KK; k++) {
        const float* Vp = bank_vals + ((size_t)(w * NN) + ix[k]) * FF + lane * 16;
        #pragma unroll
        for (int c = 0; c < 4; c++) v4[k][c] = *(const float4*)(Vp + 4 * c);
    }

    // partials: m (8), G diag real (4), G offdiag (12) -> 24, all on RAW bank vecs
    float part[24];
    #pragma unroll
    for (int t = 0; t < 24; t++) part[t] = 0.f;
    #pragma unroll
    for (int c = 0; c < 4; c++) {
        #pragma unroll
        for (int e = 0; e < 2; e++) {
            float prr = e ? p4[c].z : p4[c].x;
            float pii = e ? p4[c].w : p4[c].y;
            float vr[KK], vi[KK];
            #pragma unroll
            for (int k = 0; k < KK; k++) {
                vr[k] = e ? v4[k][c].z : v4[k][c].x;
                vi[k] = e ? v4[k][c].w : v4[k][c].y;
            }
            #pragma unroll
            for (int k = 0; k < KK; k++) {
                part[2 * k]     += vr[k] * prr + vi[k] * pii;   // conj(v)·psi
                part[2 * k + 1] += vr[k] * pii - vi[k] * prr;
                part[8 + k]     += vr[k] * vr[k] + vi[k] * vi[k];
            }
            int t = 12;
            #pragma unroll
            for (int k = 0; k < KK; k++)
                #pragma unroll
                for (int j = k + 1; j < KK; j++) {
                    part[t]     += vr[k] * vr[j] + vi[k] * vi[j];
                    part[t + 1] += vr[k] * vi[j] - vi[k] * vr[j];
                    t += 2;
                }
        }
    }
    // wave butterfly reduce (one wave == one (b,h), so this is the full sum)
    #pragma unroll
    for (int m = 1; m < 64; m <<= 1)
        #pragma unroll
        for (int t = 0; t < 24; t++) part[t] += __shfl_xor(part[t], m, 64);

    // scale by top-k weights: G = D G'' D, m = D m''
    float mr[KK], mi[KK], Gr[KK][KK], Gi[KK][KK];
    #pragma unroll
    for (int k = 0; k < KK; k++) {
        mr[k] = part[2 * k] * wk[k];
        mi[k] = part[2 * k + 1] * wk[k];
        Gr[k][k] = part[8 + k] * wk[k] * wk[k] + EPSV;
        Gi[k][k] = 0.f;
    }
    {
        int t = 12;
        #pragma unroll
        for (int k = 0; k < KK; k++)
            #pragma unroll
            for (int j = k + 1; j < KK; j++) {
                float s = wk[k] * wk[j];
                Gr[k][j] = part[t] * s;  Gi[k][j] = part[t + 1] * s;
                Gr[j][k] = Gr[k][j];     Gi[j][k] = -Gi[k][j];
                t += 2;
            }
    }

    // complex Cholesky G = L L^H  (redundant per lane — 4x4, cheap)
    float Lr[KK][KK], Li[KK][KK];
    #pragma unroll
    for (int j = 0; j < KK; j++) {
        float s = Gr[j][j];
        #pragma unroll
        for (int p = 0; p < KK; p++) if (p < j) s -= Lr[j][p] * Lr[j][p] + Li[j][p] * Li[j][p];
        float ljj = sqrtf(fmaxf(s, 1e-30f));
        Lr[j][j] = ljj; Li[j][j] = 0.f;
        float inv = 1.0f / ljj;
        #pragma unroll
        for (int k = 0; k < KK; k++) {
            if (k > j) {
                float ar = Gr[k][j], ai = Gi[k][j];
                #pragma unroll
                for (int p = 0; p < KK; p++) if (p < j) {
                    ar -= Lr[k][p] * Lr[j][p] + Li[k][p] * Li[j][p];
                    ai -= Li[k][p] * Lr[j][p] - Lr[k][p] * Li[j][p];
                }
                Lr[k][j] = ar * inv; Li[k][j] = ai * inv;
            }
        }
    }
    float yr[KK], yi[KK];
    #pragma unroll
    for (int j = 0; j < KK; j++) {
        float ar = mr[j], ai = mi[j];
        #pragma unroll
        for (int p = 0; p < KK; p++) if (p < j) {
            ar -= Lr[j][p] * yr[p] - Li[j][p] * yi[p];
            ai -= Lr[j][p] * yi[p] + Li[j][p] * yr[p];
        }
        float inv = 1.0f / Lr[j][j];
        yr[j] = ar * inv; yi[j] = ai * inv;
    }
    float xr[KK], xi2[KK];
    #pragma unroll
    for (int j = KK - 1; j >= 0; j--) {
        float ar = yr[j], ai = yi[j];
        #pragma unroll
        for (int p = 0; p < KK; p++) if (p > j) {
            ar -= Lr[p][j] * xr[p] + Li[p][j] * xi2[p];
            ai -= Lr[p][j] * xi2[p] - Li[p][j] * xr[p];
        }
        float inv = 1.0f / Lr[j][j];
        xr[j] = ar * inv; xi2[j] = ai * inv;
    }
    // fold weights into coeff: proj = sum_k v_k * (w_k x_k)
    float cxr[KK], cxi[KK];
    #pragma unroll
    for (int k = 0; k < KK; k++) { cxr[k] = xr[k] * wk[k]; cxi[k] = xi2[k] * wk[k]; }

    float4 pj[4];
    float sqp = 0.f;
    #pragma unroll
    for (int c = 0; c < 4; c++) {
        float ar0 = 0.f, ai0 = 0.f, ar1 = 0.f, ai1 = 0.f;
        #pragma unroll
        for (int k = 0; k < KK; k++) {
            ar0 += v4[k][c].x * cxr[k] - v4[k][c].y * cxi[k];
            ai0 += v4[k][c].x * cxi[k] + v4[k][c].y * cxr[k];
            ar1 += v4[k][c].z * cxr[k] - v4[k][c].w * cxi[k];
            ai1 += v4[k][c].z * cxi[k] + v4[k][c].w * cxr[k];
        }
        pj[c].x = ar0; pj[c].y = ai0; pj[c].z = ar1; pj[c].w = ai1;
        sqp += ar0 * ar0 + ai0 * ai0 + ar1 * ar1 + ai1 * ai1;
    }
    #pragma unroll
    for (int m = 1; m < 64; m <<= 1) sqp += __shfl_xor(sqp, m, 64);
    float rn = 1.0f / sqrtf(fmaxf(sqp, 1e-6f));

    float4 o0, o1, o2, o3;
    o0.x = pj[0].x * rn; o0.y = pj[0].y * rn; o0.z = pj[0].z * rn; o0.w = pj[0].w * rn;
    o1.x = pj[1].x * rn; o1.y = pj[1].y * rn; o1.z = pj[1].z * rn; o1.w = pj[1].w * rn;
    o2.x = pj[2].x * rn; o2.y = pj[2].y * rn; o2.z = pj[2].z * rn; o2.w = pj[2].w * rn;
    o3.x = pj[3].x * rn; o3.y = pj[3].y * rn; o3.z = pj[3].z * rn; o3.w = pj[3].w * rn;
    *(float4*)&Pn[w][lane * 16 + 0]  = o0;
    *(float4*)&Pn[w][lane * 16 + 4]  = o1;
    *(float4*)&Pn[w][lane * 16 + 8]  = o2;
    *(float4*)&Pn[w][lane * 16 + 12] = o3;
    if (!is_last) {
        half8 wa, wb;
        wa[0] = (_Float16)o0.x; wa[1] = (_Float16)o0.y; wa[2] = (_Float16)o0.z; wa[3] = (_Float16)o0.w;
        wa[4] = (_Float16)o1.x; wa[5] = (_Float16)o1.y; wa[6] = (_Float16)o1.z; wa[7] = (_Float16)o1.w;
        wb[0] = (_Float16)o2.x; wb[1] = (_Float16)o2.y; wb[2] = (_Float16)o2.z; wb[3] = (_Float16)o2.w;
        wb[4] = (_Float16)o3.x; wb[5] = (_Float16)o3.y; wb[6] = (_Float16)o3.z; wb[7] = (_Float16)o3.w;
        ushort_t* Pd = psi_h + (size_t)bh * FF + lane * 16;
        *(half8*)(Pd)     = wa;
        *(half8*)(Pd + 8) = wb;
    }
    __syncthreads();

    // ---------- halt phase: thread t owns floats 4t..4t+3 (2 complex) ----------
    int t4 = tid * 4;
    float4 a0 = *(const float4*)&Pn[0][t4];
    float4 a1 = *(const float4*)&Pn[1][t4];
    float4 a2 = *(const float4*)&Pn[2][t4];
    float4 a3 = *(const float4*)&Pn[3][t4];
    float4 pool;
    pool.x = 0.25f * (a0.x + a1.x + a2.x + a3.x);
    pool.y = 0.25f * (a0.y + a1.y + a2.y + a3.y);
    pool.z = 0.25f * (a0.z + a1.z + a2.z + a3.z);
    pool.w = 0.25f * (a0.w + a1.w + a2.w + a3.w);

    float pt[9];
    #pragma unroll
    for (int h = 0; h < HH; h++) {
        float4 u = *(const float4*)&u_halt[h * FF + t4];
        pt[2 * h]     = u.x * pool.x + u.y * pool.y + u.z * pool.z + u.w * pool.w;
        pt[2 * h + 1] = u.x * pool.y - u.y * pool.x + u.z * pool.w - u.w * pool.z;
    }
    pt[8] = pool.x * pool.x + pool.y * pool.y + pool.z * pool.z + pool.w * pool.w;
    #pragma unroll
    for (int m = 1; m < 64; m <<= 1)
        #pragma unroll
        for (int t = 0; t < 9; t++) pt[t] += __shfl_xor(pt[t], m, 64);
    if (lane == 0) {
        #pragma unroll
        for (int t = 0; t < 9; t++) xw[w][t] = pt[t];
    }
    __syncthreads();
    float red[9];
    #pragma unroll
    for (int t = 0; t < 9; t++) red[t] = xw[0][t] + xw[1][t] + xw[2][t] + xw[3][t];
    float ns = red[8] + EPSV;

    float hm0 = head_mix[0], hm1 = head_mix[1], hm2 = head_mix[2], hm3 = head_mix[3];
    float hmx = fmaxf(fmaxf(hm0, hm1), fmaxf(hm2, hm3));
    float he[4] = {expf(hm0 - hmx), expf(hm1 - hmx), expf(hm2 - hmx), expf(hm3 - hmx)};
    float hsum = he[0] + he[1] + he[2] + he[3];

    float wgt[4], addc[4], newcum[4]; int newhl[4];
    int idxb = b * HH;
    #pragma unroll
    for (int h = 0; h < HH; h++) {
        float cr = red[2 * h] * norm_inv[h], ci = red[2 * h + 1] * norm_inv[h];
        float alpha = (cr * cr + ci * ci) / ns;
        float beta = 1.0f - alpha;
        float gamma = cr * cr / ns;
        float lg[3];
        #pragma unroll
        for (int j = 0; j < 3; j++)
            lg[j] = alpha * W_halt[(h * 3 + 0) * 3 + j] + beta * W_halt[(h * 3 + 1) * 3 + j] +
                    gamma * W_halt[(h * 3 + 2) * 3 + j] + b_halt[h * 3 + j];
        float mx = fmaxf(lg[0], fmaxf(lg[1], lg[2]));
        float e0 = expf(lg[0] - mx), e1 = expf(lg[1] - mx), e2 = expf(lg[2] - mx);
        float p_halt = (e0 + e1) / (e0 + e1 + e2);
        float cm = cum[idxb + h];
        int hl = halted[idxb + h];
        float would = cm + p_halt;
        int halts_now = (would >= THRESHV) || is_last;
        int active = hl ? 0 : 1;
        wgt[h]  = active ? (halts_now ? (1.0f - cm) : p_halt) : 0.0f;
        addc[h] = active ? p_halt : 0.0f;
        newcum[h] = (active && !halts_now) ? would : cm;
        newhl[h]  = hl || (active && halts_now);
    }
    __syncthreads();   // all threads read cum/halted before update
    if (tid < HH) {
        cost[idxb + tid] += addc[tid];
        cum[idxb + tid] = newcum[tid];
        halted[idxb + tid] = newhl[tid];
    }
    float hwv[4];
    #pragma unroll
    for (int h = 0; h < HH; h++) hwv[h] = (he[h] / hsum) * wgt[h];

    size_t mo = (size_t)b * FF + t4;
    float4 m4 = *(const float4*)&merged[mo];
    m4.x += hwv[0] * a0.x + hwv[1] * a1.x + hwv[2] * a2.x + hwv[3] * a3.x;
    m4.y += hwv[0] * a0.y + hwv[1] * a1.y + hwv[2] * a2.y + hwv[3] * a3.y;
    m4.z += hwv[0] * a0.z + hwv[1] * a1.z + hwv[2] * a2.z + hwv[3] * a3.z;
    m4.w += hwv[0] * a0.w + hwv[1] * a1.w + hwv[2] * a2.w + hwv[3] * a3.w;
    if (is_last) {
        // fused k_out: out = psi + s*(merged_final - psi)
        float4 pp = *(const float4*)&psi[mo];
        float os = out_scale[0];
        float4 ov;
        ov.x = pp.x + os * (m4.x - pp.x);
        ov.y = pp.y + os * (m4.y - pp.y);
        ov.z = pp.z + os * (m4.z - pp.z);
        ov.w = pp.w + os * (m4.w - pp.w);
        *(float4*)&outbuf[mo] = ov;
    } else {
        *(float4*)&merged[mo] = m4;
        // feat for next iteration's GEMM = pooled psi_next, bf16
        us4 fb;
        fb.x = f2bf(pool.x); fb.y = f2bf(pool.y); fb.z = f2bf(pool.z); fb.w = f2bf(pool.w);
        *(us4*)&feat[mo] = fb;
    }
}

__global__ void k_costmean(const float* __restrict__ cost, float* __restrict__ out, int n) {
    __shared__ float red[256];
    int tid = threadIdx.x;
    float s = 0.f;
    for (int i = tid; i < n; i += 256) s += cost[i];
    red[tid] = s; __syncthreads();
    for (int off = 128; off > 0; off >>= 1) {
        if (tid < off) red[tid] += red[tid + off];
        __syncthreads();
    }
    if (tid == 0) out[0] = red[0] / (float)n;
}

extern "C" void kernel_launch(void* const* d_in, const int* in_sizes, int n_in,
                              void* d_out, int out_size, void* d_ws, size_t ws_size,
                              hipStream_t stream) {
    const float* psi       = (const float*)d_in[0];
    const float* bank_keys = (const float*)d_in[1];
    const float* bank_vals = (const float*)d_in[2];
    const float* u_halt    = (const float*)d_in[3];
    const float* W_halt    = (const float*)d_in[4];
    const float* b_halt    = (const float*)d_in[5];
    const float* head_mix  = (const float*)d_in[6];
    const float* out_scale = (const float*)d_in[7];
    float* out = (float*)d_out;

    const int BT = in_sizes[0] / FF;    // 4096

    float* ws = (float*)d_ws;
    size_t off = 0;
    ushort_t* psi_h = (ushort_t*)(ws + off); off += (size_t)BT * HH * FF / 2;  // f16
    float* merged = ws + off; off += (size_t)BT * FF;     // zero region starts here
    float* cum    = ws + off; off += (size_t)BT * HH;
    float* costv  = ws + off; off += (size_t)BT * HH;
    int*   halted = (int*)(ws + off); off += (size_t)BT * HH;
    float* topw   = ws + off; off += (size_t)BT * HH * KK;
    int*   topi   = (int*)(ws + off); off += (size_t)BT * HH * KK;
    float* norminv = ws + off; off += 16;
    ushort_t* feat_bf = (ushort_t*)(ws + off); off += (size_t)BT * FF / 2;
    ushort_t* keys_bf = (ushort_t*)(ws + off); off += (size_t)HH * NN * FF / 2;
    ushort_t* scores = (ushort_t*)(ws + off);   // f16, BT*HH*NN shorts (~67 MB)

    hipMemsetAsync(merged, 0, ((size_t)BT * FF + 3 * (size_t)BT * HH) * sizeof(float), stream);
    k_unorm<<<1, 256, 0, stream>>>(u_halt, norminv);
    int tot_keys = HH * NN * FF;
    k_cvt_bf4<<<(tot_keys / 4 + 255) / 256, 256, 0, stream>>>(bank_keys, keys_bf, tot_keys / 4);
    int tot_bf = BT * FF;
    k_cvt_bf4<<<(tot_bf / 4 + 255) / 256, 256, 0, stream>>>(psi, feat_bf, tot_bf / 4);  // iter-0 feat = psi

    for (int it = 0; it < TMAXI; ++it) {
        k_gemm_mfma<<<dim3((HH * NN) / BN, BT / BM), 256, 0, stream>>>(feat_bf, keys_bf, scores);
        k_softtop<<<dim3((BT * HH) / 4), 256, 0, stream>>>(scores, topw, topi, 0);
        k_fused<<<BT, 256, 0, stream>>>(psi, psi_h, bank_vals, topw, topi, u_halt, norminv,
                                        W_halt, b_halt, head_mix, merged, feat_bf,
                                        cum, costv, halted, out_scale, out,
                                        (it == 0) ? 1 : 0, (it == TMAXI - 1) ? 1 : 0);
    }
    k_costmean<<<1, 256, 0, stream>>>(costv, out + tot_bf, BT * HH);
}

// Round 12
// 1040.216 us; speedup vs baseline: 1.2601x; 1.2601x over previous
//
#include <hip/hip_runtime.h>
#include <math.h>

#define HH 4
#define DD 512
#define FF 1024          // 2*DD floats per complex vector
#define NN 2048
#define KK 4
#define TMAXI 4
#define THRESHV 0.99f
#define EPSV 1e-6f

typedef unsigned short ushort_t;
typedef __attribute__((ext_vector_type(8))) __bf16 bf16x8;
typedef __attribute__((ext_vector_type(8))) _Float16 half8;
typedef __attribute__((ext_vector_type(4))) float f32x4;
typedef __attribute__((ext_vector_type(4))) unsigned short us4;

__device__ __forceinline__ unsigned short f2bf(float x) {
    unsigned int u = __float_as_uint(x);
    unsigned int r = (u + 0x7FFF + ((u >> 16) & 1)) >> 16;   // round-to-nearest-even
    return (unsigned short)r;
}

__device__ __forceinline__ float fast_rcp(float x) { return __builtin_amdgcn_rcpf(x); }

typedef __attribute__((address_space(3))) unsigned int lds_u32;
typedef __attribute__((address_space(1))) const unsigned int glb_u32;
__device__ __forceinline__ void gl_lds16(const void* g, void* s) {
    __builtin_amdgcn_global_load_lds((glb_u32*)g, (lds_u32*)s, 16, 0, 0);
}

// ---------------- u_halt norms ----------------
__global__ void k_unorm(const float* __restrict__ u_halt, float* __restrict__ norm_inv) {
    __shared__ float red[256];
    int tid = threadIdx.x;
    for (int h = 0; h < HH; ++h) {
        float s = 0.f;
        for (int i = tid; i < FF; i += 256) { float v = u_halt[h * FF + i]; s += v * v; }
        red[tid] = s; __syncthreads();
        for (int off = 128; off > 0; off >>= 1) {
            if (tid < off) red[tid] += red[tid + off];
            __syncthreads();
        }
        if (tid == 0) norm_inv[h] = 1.0f / sqrtf(red[0] + EPSV);
        __syncthreads();
    }
}

// ---------------- fp32 -> bf16 cast (vectorized x4, G13) ----------------
__global__ void k_cvt_bf4(const float* __restrict__ in, ushort_t* __restrict__ out, int total4) {
    int i = blockIdx.x * 256 + threadIdx.x;
    if (i >= total4) return;
    float4 v = ((const float4*)in)[i];
    us4 o;
    o.x = f2bf(v.x); o.y = f2bf(v.y); o.z = f2bf(v.z); o.w = f2bf(v.w);
    ((us4*)out)[i] = o;
}

// ---------------- scores GEMM (bf16 MFMA, BK=64, T2 both-sides XOR swizzle) ----------------
// C stored as f16 (round-8 win: halves the scores round-trip).
#define BM 128
#define BN 128
#define BKE 64
__global__ __launch_bounds__(256) void k_gemm_mfma(const ushort_t* __restrict__ A,
                                                   const ushort_t* __restrict__ B,
                                                   ushort_t* __restrict__ C) {
    __shared__ __align__(16) ushort_t As[BM * BKE];   // 16 KB
    __shared__ __align__(16) ushort_t Bs[BN * BKE];   // 16 KB
    int tid = threadIdx.x;
    int lane = tid & 63, w = tid >> 6;
    int row0 = blockIdx.y * BM, col0 = blockIdx.x * BN;

    int srow = lane >> 3;
    int schunk = (lane & 7) ^ srow;            // pre-swizzled global chunk
    const ushort_t* gA = A + (size_t)(row0 + w * 32 + srow) * FF + schunk * 8;
    const ushort_t* gB = B + (size_t)(col0 + w * 32 + srow) * FF + schunk * 8;
    ushort_t* sA = As + (w * 32) * BKE;
    ushort_t* sB = Bs + (w * 32) * BKE;

    int fr = lane & 15;
    int q  = lane >> 4;                        // 0..3
    int wr0 = (w >> 1) * 64, wc0 = (w & 1) * 64;

    f32x4 acc[4][4] = {};

    for (int kb = 0; kb < FF; kb += BKE) {
        #pragma unroll
        for (int i = 0; i < 4; i++) {
            gl_lds16(gA + kb + (size_t)(8 * i) * FF, sA + (8 * i) * BKE);
            gl_lds16(gB + kb + (size_t)(8 * i) * FF, sB + (8 * i) * BKE);
        }
        __syncthreads();
        bf16x8 af[2][4], bfv[2][4];
        #pragma unroll
        for (int hf = 0; hf < 2; hf++) {
            int ck = ((4 * hf + q) ^ (fr & 7)) * 8;   // swizzled short offset in row
            #pragma unroll
            for (int i = 0; i < 4; i++) {
                af[hf][i]  = *(const bf16x8*)&As[(wr0 + 16 * i + fr) * BKE + ck];
                bfv[hf][i] = *(const bf16x8*)&Bs[(wc0 + 16 * i + fr) * BKE + ck];
            }
        }
        #pragma unroll
        for (int hf = 0; hf < 2; hf++)
            #pragma unroll
            for (int i = 0; i < 4; i++)
                #pragma unroll
                for (int j = 0; j < 4; j++)
                    acc[i][j] = __builtin_amdgcn_mfma_f32_16x16x32_bf16(af[hf][i], bfv[hf][j], acc[i][j], 0, 0, 0);
        __syncthreads();
    }

    int crow = (lane >> 4) * 4;
    int ccol = lane & 15;
    #pragma unroll
    for (int i = 0; i < 4; i++)
        #pragma unroll
        for (int r = 0; r < 4; r++) {
            ushort_t* Cr = C + (size_t)(row0 + wr0 + 16 * i + crow + r) * (HH * NN) + col0 + wc0 + ccol;
            #pragma unroll
            for (int j = 0; j < 4; j++) {
                _Float16 hv = (_Float16)acc[i][j][r];
                Cr[16 * j] = *(ushort_t*)&hv;
            }
        }
}

// ---------------- softmax + top-4 per (row, head) ----------------
// One WAVE per (row, head): 2048 f16 scores -> 32 floats/lane. (round-8 proven)
__global__ __launch_bounds__(256) void k_softtop(const ushort_t* __restrict__ Sc,
                                                 float* __restrict__ topw, int* __restrict__ topi,
                                                 int row0) {
    int tid = threadIdx.x;
    int w = tid >> 6, lane = tid & 63;
    int g = blockIdx.x * 4 + w;          // (row, head) pair within chunk
    int r = g >> 2;
    int h = g & 3;
    const ushort_t* S = Sc + (size_t)r * (HH * NN) + h * NN + lane * 8;
    float f0[8], f1[8], f2[8], f3[8];
    {
        half8 h0 = *(const half8*)(S);
        half8 h1 = *(const half8*)(S + 512);
        half8 h2 = *(const half8*)(S + 1024);
        half8 h3 = *(const half8*)(S + 1536);
        #pragma unroll
        for (int e = 0; e < 8; e++) {
            f0[e] = (float)h0[e]; f1[e] = (float)h1[e];
            f2[e] = (float)h2[e]; f3[e] = (float)h3[e];
        }
    }

    // row max
    float bm = f0[0];
    #pragma unroll
    for (int e = 0; e < 8; e++) {
        bm = fmaxf(bm, fmaxf(fmaxf(f0[e], f1[e]), fmaxf(f2[e], f3[e])));
    }
    #pragma unroll
    for (int m = 1; m < 64; m <<= 1) bm = fmaxf(bm, __shfl_xor(bm, m, 64));

    // sum of exp
    float se = 0.f;
    #pragma unroll
    for (int e = 0; e < 8; e++)
        se += __expf(f0[e] - bm) + __expf(f1[e] - bm) + __expf(f2[e] - bm) + __expf(f3[e] - bm);
    #pragma unroll
    for (int m = 1; m < 64; m <<= 1) se += __shfl_xor(se, m, 64);
    float Zinv = fast_rcp(se);

    int gbh = (row0 + r) * HH + h;
    int base = lane * 8;
    #pragma unroll
    for (int k = 0; k < KK; k++) {
        float bv = -INFINITY; int bi = NN;
        #pragma unroll
        for (int e = 0; e < 8; e++) {
            if (f0[e] > bv) { bv = f0[e]; bi = base + e; }
        }
        #pragma unroll
        for (int e = 0; e < 8; e++) {
            if (f1[e] > bv) { bv = f1[e]; bi = 512 + base + e; }
        }
        #pragma unroll
        for (int e = 0; e < 8; e++) {
            if (f2[e] > bv) { bv = f2[e]; bi = 1024 + base + e; }
        }
        #pragma unroll
        for (int e = 0; e < 8; e++) {
            if (f3[e] > bv) { bv = f3[e]; bi = 1536 + base + e; }
        }
        #pragma unroll
        for (int m = 1; m < 64; m <<= 1) {
            float ov = __shfl_xor(bv, m, 64);
            int   oi = __shfl_xor(bi, m, 64);
            if (ov > bv || (ov == bv && oi < bi)) { bv = ov; bi = oi; }
        }
        if (lane == 0) {
            topw[gbh * KK + k] = __expf(bv - bm) * Zinv;
            topi[gbh * KK + k] = bi;
        }
        if (k < KK - 1) {
            #pragma unroll
            for (int e = 0; e < 8; e++) {
                if (base + e == bi)        f0[e] = -INFINITY;
                if (512 + base + e == bi)  f1[e] = -INFINITY;
                if (1024 + base + e == bi) f2[e] = -INFINITY;
                if (1536 + base + e == bi) f3[e] = -INFINITY;
            }
        }
    }
}

// ---------------- fused solve + halt + pool ----------------
// block = token b; wave w = head h; lane owns 8 complex elems.
// Body = round-0/8 PROVEN version, f32 psi_h (round-11's f16 pack crossed the
// 128-VGPR cliff: 116->132, 4->3 waves, +54% time — the solve-phase register
// peak at 116 has only 12 regs of headroom; NO body edits allowed).
// Only TAIL-phase edits (after solve regs die): (a) last iter computes `out`
// directly (k_out fused); (b) first iter WRITES merged (it's zero) — no read,
// and no 67MB memset needed.
__global__ __launch_bounds__(256) void k_fused(const float* __restrict__ psi,
                                               float* __restrict__ psi_h,
                                               const float* __restrict__ bank_vals,
                                               const float* __restrict__ topw,
                                               const int* __restrict__ topi,
                                               const float* __restrict__ u_halt,
                                               const float* __restrict__ norm_inv,
                                               const float* __restrict__ W_halt,
                                               const float* __restrict__ b_halt,
                                               const float* __restrict__ head_mix,
                                               float* __restrict__ merged,
                                               ushort_t* __restrict__ feat,
                                               float* __restrict__ cum,
                                               float* __restrict__ cost,
                                               int* __restrict__ halted,
                                               const float* __restrict__ out_scale,
                                               float* __restrict__ outbuf,
                                               int first, int is_last) {
    __shared__ float Pn[HH][FF];     // psi_next staging (16 KB)
    __shared__ float xw[4][9];
    int b = blockIdx.x;
    int tid = threadIdx.x;
    int w = tid >> 6, lane = tid & 63;
    int bh = b * HH + w;

    float wk[KK]; int ix[KK];
    #pragma unroll
    for (int k = 0; k < KK; k++) { wk[k] = topw[bh * KK + k]; ix[k] = topi[bh * KK + k]; }

    const float* Pr = first ? (psi + (size_t)b * FF) : (psi_h + (size_t)bh * FF);
    float4 p4[4], v4[KK][4];
    #pragma unroll
    for (int c = 0; c < 4; c++) p4[c] = *(const float4*)(Pr + lane * 16 + 4 * c);
    #pragma unroll
    for (int k = 0; k < KK; k++) {
        const float* Vp = bank_vals + ((size_t)(w * NN) + ix[k]) * FF + lane * 16;
        #pragma unroll
        for (int c = 0; c < 4; c++) v4[k][c] = *(const float4*)(Vp + 4 * c);
    }

    // partials: m (8), G diag real (4), G offdiag (12) -> 24, all on RAW bank vecs
    float part[24];
    #pragma unroll
    for (int t = 0; t < 24; t++) part[t] = 0.f;
    #pragma unroll
    for (int c = 0; c < 4; c++) {
        #pragma unroll
        for (int e = 0; e < 2; e++) {
            float prr = e ? p4[c].z : p4[c].x;
            float pii = e ? p4[c].w : p4[c].y;
            float vr[KK], vi[KK];
            #pragma unroll
            for (int k = 0; k < KK; k++) {
                vr[k] = e ? v4[k][c].z : v4[k][c].x;
                vi[k] = e ? v4[k][c].w : v4[k][c].y;
            }
            #pragma unroll
            for (int k = 0; k < KK; k++) {
                part[2 * k]     += vr[k] * prr + vi[k] * pii;   // conj(v)·psi
                part[2 * k + 1] += vr[k] * pii - vi[k] * prr;
                part[8 + k]     += vr[k] * vr[k] + vi[k] * vi[k];
            }
            int t = 12;
            #pragma unroll
            for (int k = 0; k < KK; k++)
                #pragma unroll
                for (int j = k + 1; j < KK; j++) {
                    part[t]     += vr[k] * vr[j] + vi[k] * vi[j];
                    part[t + 1] += vr[k] * vi[j] - vi[k] * vr[j];
                    t += 2;
                }
        }
    }
    // wave butterfly reduce (one wave == one (b,h), so this is the full sum)
    #pragma unroll
    for (int m = 1; m < 64; m <<= 1)
        #pragma unroll
        for (int t = 0; t < 24; t++) part[t] += __shfl_xor(part[t], m, 64);

    // scale by top-k weights: G = D G'' D, m = D m''
    float mr[KK], mi[KK], Gr[KK][KK], Gi[KK][KK];
    #pragma unroll
    for (int k = 0; k < KK; k++) {
        mr[k] = part[2 * k] * wk[k];
        mi[k] = part[2 * k + 1] * wk[k];
        Gr[k][k] = part[8 + k] * wk[k] * wk[k] + EPSV;
        Gi[k][k] = 0.f;
    }
    {
        int t = 12;
        #pragma unroll
        for (int k = 0; k < KK; k++)
            #pragma unroll
            for (int j = k + 1; j < KK; j++) {
                float s = wk[k] * wk[j];
                Gr[k][j] = part[t] * s;  Gi[k][j] = part[t + 1] * s;
                Gr[j][k] = Gr[k][j];     Gi[j][k] = -Gi[k][j];
                t += 2;
            }
    }

    // complex Cholesky G = L L^H  (redundant per lane — 4x4, cheap)
    float Lr[KK][KK], Li[KK][KK];
    #pragma unroll
    for (int j = 0; j < KK; j++) {
        float s = Gr[j][j];
        #pragma unroll
        for (int p = 0; p < KK; p++) if (p < j) s -= Lr[j][p] * Lr[j][p] + Li[j][p] * Li[j][p];
        float ljj = sqrtf(fmaxf(s, 1e-30f));
        Lr[j][j] = ljj; Li[j][j] = 0.f;
        float inv = 1.0f / ljj;
        #pragma unroll
        for (int k = 0; k < KK; k++) {
            if (k > j) {
                float ar = Gr[k][j], ai = Gi[k][j];
                #pragma unroll
                for (int p = 0; p < KK; p++) if (p < j) {
                    ar -= Lr[k][p] * Lr[j][p] + Li[k][p] * Li[j][p];
                    ai -= Li[k][p] * Lr[j][p] - Lr[k][p] * Li[j][p];
                }
                Lr[k][j] = ar * inv; Li[k][j] = ai * inv;
            }
        }
    }
    float yr[KK], yi[KK];
    #pragma unroll
    for (int j = 0; j < KK; j++) {
        float ar = mr[j], ai = mi[j];
        #pragma unroll
        for (int p = 0; p < KK; p++) if (p < j) {
            ar -= Lr[j][p] * yr[p] - Li[j][p] * yi[p];
            ai -= Lr[j][p] * yi[p] + Li[j][p] * yr[p];
        }
        float inv = 1.0f / Lr[j][j];
        yr[j] = ar * inv; yi[j] = ai * inv;
    }
    float xr[KK], xi2[KK];
    #pragma unroll
    for (int j = KK - 1; j >= 0; j--) {
        float ar = yr[j], ai = yi[j];
        #pragma unroll
        for (int p = 0; p < KK; p++) if (p > j) {
            ar -= Lr[p][j] * xr[p] + Li[p][j] * xi2[p];
            ai -= Lr[p][j] * xi2[p] - Li[p][j] * xr[p];
        }
        float inv = 1.0f / Lr[j][j];
        xr[j] = ar * inv; xi2[j] = ai * inv;
    }
    // fold weights into coeff: proj = sum_k v_k * (w_k x_k)
    float cxr[KK], cxi[KK];
    #pragma unroll
    for (int k = 0; k < KK; k++) { cxr[k] = xr[k] * wk[k]; cxi[k] = xi2[k] * wk[k]; }

    float4 pj[4];
    float sqp = 0.f;
    #pragma unroll
    for (int c = 0; c < 4; c++) {
        float ar0 = 0.f, ai0 = 0.f, ar1 = 0.f, ai1 = 0.f;
        #pragma unroll
        for (int k = 0; k < KK; k++) {
            ar0 += v4[k][c].x * cxr[k] - v4[k][c].y * cxi[k];
            ai0 += v4[k][c].x * cxi[k] + v4[k][c].y * cxr[k];
            ar1 += v4[k][c].z * cxr[k] - v4[k][c].w * cxi[k];
            ai1 += v4[k][c].z * cxi[k] + v4[k][c].w * cxr[k];
        }
        pj[c].x = ar0; pj[c].y = ai0; pj[c].z = ar1; pj[c].w = ai1;
        sqp += ar0 * ar0 + ai0 * ai0 + ar1 * ar1 + ai1 * ai1;
    }
    #pragma unroll
    for (int m = 1; m < 64; m <<= 1) sqp += __shfl_xor(sqp, m, 64);
    float rn = 1.0f / sqrtf(fmaxf(sqp, 1e-6f));

    float* Pdst = psi_h + (size_t)bh * FF + lane * 16;
    #pragma unroll
    for (int c = 0; c < 4; c++) {
        float4 o; o.x = pj[c].x * rn; o.y = pj[c].y * rn; o.z = pj[c].z * rn; o.w = pj[c].w * rn;
        if (!is_last) *(float4*)(Pdst + 4 * c) = o;   // psi_h unused after last iter
        *(float4*)&Pn[w][lane * 16 + 4 * c] = o;
    }
    __syncthreads();

    // ---------- halt phase: thread t owns floats 4t..4t+3 (2 complex) ----------
    int t4 = tid * 4;
    float4 a0 = *(const float4*)&Pn[0][t4];
    float4 a1 = *(const float4*)&Pn[1][t4];
    float4 a2 = *(const float4*)&Pn[2][t4];
    float4 a3 = *(const float4*)&Pn[3][t4];
    float4 pool;
    pool.x = 0.25f * (a0.x + a1.x + a2.x + a3.x);
    pool.y = 0.25f * (a0.y + a1.y + a2.y + a3.y);
    pool.z = 0.25f * (a0.z + a1.z + a2.z + a3.z);
    pool.w = 0.25f * (a0.w + a1.w + a2.w + a3.w);

    float pt[9];
    #pragma unroll
    for (int h = 0; h < HH; h++) {
        float4 u = *(const float4*)&u_halt[h * FF + t4];
        pt[2 * h]     = u.x * pool.x + u.y * pool.y + u.z * pool.z + u.w * pool.w;
        pt[2 * h + 1] = u.x * pool.y - u.y * pool.x + u.z * pool.w - u.w * pool.z;
    }
    pt[8] = pool.x * pool.x + pool.y * pool.y + pool.z * pool.z + pool.w * pool.w;
    #pragma unroll
    for (int m = 1; m < 64; m <<= 1)
        #pragma unroll
        for (int t = 0; t < 9; t++) pt[t] += __shfl_xor(pt[t], m, 64);
    if (lane == 0) {
        #pragma unroll
        for (int t = 0; t < 9; t++) xw[w][t] = pt[t];
    }
    __syncthreads();
    float red[9];
    #pragma unroll
    for (int t = 0; t < 9; t++) red[t] = xw[0][t] + xw[1][t] + xw[2][t] + xw[3][t];
    float ns = red[8] + EPSV;

    float hm0 = head_mix[0], hm1 = head_mix[1], hm2 = head_mix[2], hm3 = head_mix[3];
    float hmx = fmaxf(fmaxf(hm0, hm1), fmaxf(hm2, hm3));
    float he[4] = {expf(hm0 - hmx), expf(hm1 - hmx), expf(hm2 - hmx), expf(hm3 - hmx)};
    float hsum = he[0] + he[1] + he[2] + he[3];

    float wgt[4], addc[4], newcum[4]; int newhl[4];
    int idxb = b * HH;
    #pragma unroll
    for (int h = 0; h < HH; h++) {
        float cr = red[2 * h] * norm_inv[h], ci = red[2 * h + 1] * norm_inv[h];
        float alpha = (cr * cr + ci * ci) / ns;
        float beta = 1.0f - alpha;
        float gamma = cr * cr / ns;
        float lg[3];
        #pragma unroll
        for (int j = 0; j < 3; j++)
            lg[j] = alpha * W_halt[(h * 3 + 0) * 3 + j] + beta * W_halt[(h * 3 + 1) * 3 + j] +
                    gamma * W_halt[(h * 3 + 2) * 3 + j] + b_halt[h * 3 + j];
        float mx = fmaxf(lg[0], fmaxf(lg[1], lg[2]));
        float e0 = expf(lg[0] - mx), e1 = expf(lg[1] - mx), e2 = expf(lg[2] - mx);
        float p_halt = (e0 + e1) / (e0 + e1 + e2);
        float cm = cum[idxb + h];
        int hl = halted[idxb + h];
        float would = cm + p_halt;
        int halts_now = (would >= THRESHV) || is_last;
        int active = hl ? 0 : 1;
        wgt[h]  = active ? (halts_now ? (1.0f - cm) : p_halt) : 0.0f;
        addc[h] = active ? p_halt : 0.0f;
        newcum[h] = (active && !halts_now) ? would : cm;
        newhl[h]  = hl || (active && halts_now);
    }
    __syncthreads();   // all threads read cum/halted before update
    if (tid < HH) {
        cost[idxb + tid] += addc[tid];
        cum[idxb + tid] = newcum[tid];
        halted[idxb + tid] = newhl[tid];
    }
    float hwv[4];
    #pragma unroll
    for (int h = 0; h < HH; h++) hwv[h] = (he[h] / hsum) * wgt[h];

    size_t mo = (size_t)b * FF + t4;
    float4 m4;
    if (first) {
        m4.x = 0.f; m4.y = 0.f; m4.z = 0.f; m4.w = 0.f;   // merged starts at zero — skip the read
    } else {
        m4 = *(const float4*)&merged[mo];
    }
    m4.x += hwv[0] * a0.x + hwv[1] * a1.x + hwv[2] * a2.x + hwv[3] * a3.x;
    m4.y += hwv[0] * a0.y + hwv[1] * a1.y + hwv[2] * a2.y + hwv[3] * a3.y;
    m4.z += hwv[0] * a0.z + hwv[1] * a1.z + hwv[2] * a2.z + hwv[3] * a3.z;
    m4.w += hwv[0] * a0.w + hwv[1] * a1.w + hwv[2] * a2.w + hwv[3] * a3.w;
    if (is_last) {
        // fused k_out: out = psi + s*(merged_final - psi)
        float4 pp = *(const float4*)&psi[mo];
        float os = out_scale[0];
        float4 ov;
        ov.x = pp.x + os * (m4.x - pp.x);
        ov.y = pp.y + os * (m4.y - pp.y);
        ov.z = pp.z + os * (m4.z - pp.z);
        ov.w = pp.w + os * (m4.w - pp.w);
        *(float4*)&outbuf[mo] = ov;
    } else {
        *(float4*)&merged[mo] = m4;
        // feat for next iteration's GEMM = pooled psi_next, bf16
        us4 fb;
        fb.x = f2bf(pool.x); fb.y = f2bf(pool.y); fb.z = f2bf(pool.z); fb.w = f2bf(pool.w);
        *(us4*)&feat[mo] = fb;
    }
}

__global__ void k_costmean(const float* __restrict__ cost, float* __restrict__ out, int n) {
    __shared__ float red[256];
    int tid = threadIdx.x;
    float s = 0.f;
    for (int i = tid; i < n; i += 256) s += cost[i];
    red[tid] = s; __syncthreads();
    for (int off = 128; off > 0; off >>= 1) {
        if (tid < off) red[tid] += red[tid + off];
        __syncthreads();
    }
    if (tid == 0) out[0] = red[0] / (float)n;
}

extern "C" void kernel_launch(void* const* d_in, const int* in_sizes, int n_in,
                              void* d_out, int out_size, void* d_ws, size_t ws_size,
                              hipStream_t stream) {
    const float* psi       = (const float*)d_in[0];
    const float* bank_keys = (const float*)d_in[1];
    const float* bank_vals = (const float*)d_in[2];
    const float* u_halt    = (const float*)d_in[3];
    const float* W_halt    = (const float*)d_in[4];
    const float* b_halt    = (const float*)d_in[5];
    const float* head_mix  = (const float*)d_in[6];
    const float* out_scale = (const float*)d_in[7];
    float* out = (float*)d_out;

    const int BT = in_sizes[0] / FF;    // 4096

    float* ws = (float*)d_ws;
    size_t off = 0;
    float* psi_h  = ws + off; off += (size_t)BT * HH * FF;
    float* merged = ws + off; off += (size_t)BT * FF;
    float* cum    = ws + off; off += (size_t)BT * HH;     // zero region starts here
    float* costv  = ws + off; off += (size_t)BT * HH;
    int*   halted = (int*)(ws + off); off += (size_t)BT * HH;
    float* topw   = ws + off; off += (size_t)BT * HH * KK;
    int*   topi   = (int*)(ws + off); off += (size_t)BT * HH * KK;
    float* norminv = ws + off; off += 16;
    ushort_t* feat_bf = (ushort_t*)(ws + off); off += (size_t)BT * FF / 2;
    ushort_t* keys_bf = (ushort_t*)(ws + off); off += (size_t)HH * NN * FF / 2;
    ushort_t* scores = (ushort_t*)(ws + off);   // f16, BT*HH*NN shorts (~67 MB)

    // merged no longer needs zeroing (iter-0 k_fused writes it); only cum/cost/halted.
    hipMemsetAsync(cum, 0, (3 * (size_t)BT * HH) * sizeof(float), stream);
    k_unorm<<<1, 256, 0, stream>>>(u_halt, norminv);
    int tot_keys = HH * NN * FF;
    k_cvt_bf4<<<(tot_keys / 4 + 255) / 256, 256, 0, stream>>>(bank_keys, keys_bf, tot_keys / 4);
    int tot_bf = BT * FF;
    k_cvt_bf4<<<(tot_bf / 4 + 255) / 256, 256, 0, stream>>>(psi, feat_bf, tot_bf / 4);  // iter-0 feat = psi

    for (int it = 0; it < TMAXI; ++it) {
        k_gemm_mfma<<<dim3((HH * NN) / BN, BT / BM), 256, 0, stream>>>(feat_bf, keys_bf, scores);
        k_softtop<<<dim3((BT * HH) / 4), 256, 0, stream>>>(scores, topw, topi, 0);
        k_fused<<<BT, 256, 0, stream>>>(psi, psi_h, bank_vals, topw, topi, u_halt, norminv,
                                        W_halt, b_halt, head_mix, merged, feat_bf,
                                        cum, costv, halted, out_scale, out,
                                        (it == 0) ? 1 : 0, (it == TMAXI - 1) ? 1 : 0);
    }
    k_costmean<<<1, 256, 0, stream>>>(costv, out + tot_bf, BT * HH);
}